// Round 14
// baseline (198.755 us; speedup 1.0000x reference)
//
#include <hip/hip_runtime.h>
#include <math.h>

#define NROWS 8192
#define NFEATD 500
#define NHID 128
#define NCLS 40
#define CAP 64            // max nnz/row (mean ~16.4, binomial max ~41)
#define FCIN_BLOCKS (NROWS / 8)   // 1024
#define CSR_BLOCKS  (NROWS / 4)   // 2048
#define ROWS_PB 8                 // rows per k_layer block (grid = 1024)

typedef float f32x4 __attribute__((ext_vector_type(4)));
typedef float f32x2 __attribute__((ext_vector_type(2)));

// ---------------------------------------------------------------------------
// Kernel 1 (heterogeneous): blocks [0,1024) do fcin, blocks [1024,3072) do
// CSR build. (R4/R9/R12/R13-verbatim.)
// ---------------------------------------------------------------------------
__global__ __launch_bounds__(256) void k_pre(
    const float* __restrict__ x, const float* __restrict__ w,
    const float* __restrict__ b, const float* __restrict__ c,
    const float* __restrict__ adj,
    float* __restrict__ h, float* __restrict__ h0,
    float* __restrict__ dinv, int* __restrict__ cnts, int* __restrict__ cols)
{
    __shared__ float xs[8][504];
    int tid = threadIdx.x;
    if (blockIdx.x < FCIN_BLOCKS) {
        int col = tid & 127;
        int rg = tid >> 7;
        int r0 = blockIdx.x * 8;
        for (int rr = 0; rr < 8; ++rr)
            for (int k = tid; k < NFEATD; k += 256)
                xs[rr][k] = x[(size_t)(r0 + rr) * NFEATD + k];
        __syncthreads();
        float bias = b[col];
        float acc[4] = {bias, bias, bias, bias};
        for (int k4 = 0; k4 < NFEATD / 4; ++k4) {
            int k = k4 * 4;
            f32x4 a0 = *(const f32x4*)&xs[rg * 4 + 0][k];
            f32x4 a1 = *(const f32x4*)&xs[rg * 4 + 1][k];
            f32x4 a2 = *(const f32x4*)&xs[rg * 4 + 2][k];
            f32x4 a3 = *(const f32x4*)&xs[rg * 4 + 3][k];
            float w0 = w[(k + 0) * NHID + col];
            float w1 = w[(k + 1) * NHID + col];
            float w2 = w[(k + 2) * NHID + col];
            float w3 = w[(k + 3) * NHID + col];
            acc[0] += a0.x * w0 + a0.y * w1 + a0.z * w2 + a0.w * w3;
            acc[1] += a1.x * w0 + a1.y * w1 + a1.z * w2 + a1.w * w3;
            acc[2] += a2.x * w0 + a2.y * w1 + a2.z * w2 + a2.w * w3;
            acc[3] += a3.x * w0 + a3.y * w1 + a3.z * w2 + a3.w * w3;
        }
        float cv = c[col];
#pragma unroll
        for (int rr = 0; rr < 4; ++rr) {
            float hv = 0.9f * fmaxf(acc[rr], 0.0f) + 0.1f * cv;
            size_t o = (size_t)(r0 + rg * 4 + rr) * NHID + col;
            h[o] = hv;
            h0[o] = hv;
        }
    } else {
        int bid = blockIdx.x - FCIN_BLOCKS;
        int r = bid * 4 + (tid >> 6);
        int lane = tid & 63;
        const f32x4* row4 = (const f32x4*)(adj + (size_t)r * NROWS);
        int* mycols = cols + (size_t)r * CAP;
        unsigned long long lt = (1ull << lane) - 1ull;
        int cnt = 0;
        for (int it = 0; it < NROWS / 256; ++it) {
            f32x4 v = __builtin_nontemporal_load(&row4[it * 64 + lane]);
            int base = it * 256 + 4 * lane;
            bool nz; unsigned long long m;
            nz = (v.x != 0.0f); m = __ballot(nz);
            if (nz) { int p = cnt + __popcll(m & lt); mycols[p < CAP ? p : CAP - 1] = base; }
            cnt += __popcll(m);
            nz = (v.y != 0.0f); m = __ballot(nz);
            if (nz) { int p = cnt + __popcll(m & lt); mycols[p < CAP ? p : CAP - 1] = base + 1; }
            cnt += __popcll(m);
            nz = (v.z != 0.0f); m = __ballot(nz);
            if (nz) { int p = cnt + __popcll(m & lt); mycols[p < CAP ? p : CAP - 1] = base + 2; }
            cnt += __popcll(m);
            nz = (v.w != 0.0f); m = __ballot(nz);
            if (nz) { int p = cnt + __popcll(m & lt); mycols[p < CAP ? p : CAP - 1] = base + 3; }
            cnt += __popcll(m);
        }
        if (lane == 0) {
            cnts[r] = cnt < CAP ? cnt : CAP;
            dinv[r] = rsqrtf((float)cnt + 1.0f);
        }
    }
}

// ---------------------------------------------------------------------------
// Kernel 2 (per layer, 512 threads / 8 waves): gather (1 row per wave;
// edge_dinv for layer 0, ht-based otherwise) then split-matrix + 4-way
// SPLIT-K GEMM:
//   br = tid>>8 matrix (0: ahs@wlin, 1: ss@wg)
//   kq = (tid>>6)&3 k-quarter -> 8 k4 iters per wave (R13 had 16)
//   cp = tid&63 -> cols {2cp,2cp+1} f32x2 (each weight read ONCE per block)
// 3 partial sets combined via LDS. Epilogue as R13.
// ---------------------------------------------------------------------------
__global__ __launch_bounds__(512) void k_layer(
    const float* __restrict__ hin, const float* __restrict__ h0,
    const float* __restrict__ dinv, const int* __restrict__ cnts,
    const int* __restrict__ cols,
    const float* __restrict__ wlin, const float* __restrict__ blin,
    const float* __restrict__ wg, const float* __restrict__ bg,
    float beta, float* __restrict__ htout,
    const float* __restrict__ fow, const float* __restrict__ fob,
    float* __restrict__ out, int edge_dinv, int final_layer)
{
    __shared__ float ahs[ROWS_PB][NHID];
    __shared__ float ss[ROWS_PB][NHID];
    __shared__ float red[3][2][ROWS_PB][NHID];  // [kq-1][br][row][col]
    int tid = threadIdx.x;
    int lane = tid & 63;
    int wid = tid >> 6;                          // 0..7
    int r0 = blockIdx.x * ROWS_PB;
    const float2* h2 = (const float2*)hin;
    const float2* h02 = (const float2*)h0;

    // ---- gather phase: wave wid handles row wid ----
    {
        int rr = wid;
        int r = r0 + rr;
        int n = cnts[r];
        const int* mc = cols + (size_t)r * CAP;
        float ax = 0.f, ay = 0.f;
        int e = 0;
        if (edge_dinv) {
            for (; e + 4 <= n; e += 4) {
                int j0 = mc[e], j1 = mc[e + 1], j2 = mc[e + 2], j3 = mc[e + 3];
                float d0 = dinv[j0], d1 = dinv[j1], d2 = dinv[j2], d3 = dinv[j3];
                float2 v0 = h2[(size_t)j0 * 64 + lane];
                float2 v1 = h2[(size_t)j1 * 64 + lane];
                float2 v2 = h2[(size_t)j2 * 64 + lane];
                float2 v3 = h2[(size_t)j3 * 64 + lane];
                ax += d0 * v0.x + d1 * v1.x + d2 * v2.x + d3 * v3.x;
                ay += d0 * v0.y + d1 * v1.y + d2 * v2.y + d3 * v3.y;
            }
            for (; e < n; ++e) {
                int j = mc[e];
                float dj = dinv[j];
                float2 v = h2[(size_t)j * 64 + lane];
                ax += dj * v.x;
                ay += dj * v.y;
            }
            float di = dinv[r];
            float2 vi = h2[(size_t)r * 64 + lane];
            ax = di * (ax + di * vi.x);
            ay = di * (ay + di * vi.y);
        } else {
            for (; e + 4 <= n; e += 4) {
                int j0 = mc[e], j1 = mc[e + 1], j2 = mc[e + 2], j3 = mc[e + 3];
                float2 v0 = h2[(size_t)j0 * 64 + lane];
                float2 v1 = h2[(size_t)j1 * 64 + lane];
                float2 v2 = h2[(size_t)j2 * 64 + lane];
                float2 v3 = h2[(size_t)j3 * 64 + lane];
                ax += v0.x + v1.x + v2.x + v3.x;
                ay += v0.y + v1.y + v2.y + v3.y;
            }
            for (; e < n; ++e) {
                int j = mc[e];
                float2 v = h2[(size_t)j * 64 + lane];
                ax += v.x;
                ay += v.y;
            }
            float di = dinv[r];
            float2 ti = h2[(size_t)r * 64 + lane];   // ti = dinv[r]*h[r]
            ax = di * (ax + ti.x);
            ay = di * (ay + ti.y);
        }
        float2 h0v = h02[(size_t)r * 64 + lane];
        ((float2*)&ahs[rr][0])[lane] = make_float2(ax, ay);
        ((float2*)&ss[rr][0])[lane] =
            make_float2(0.9f * ax + 0.1f * h0v.x, 0.9f * ay + 0.1f * h0v.y);
    }
    __syncthreads();

    // ---- 4-way split-k, split-matrix GEMM ----
    int br = tid >> 8;          // matrix select (wave-uniform)
    int kq = (tid >> 6) & 3;    // k-quarter (wave-uniform)
    int cp = tid & 63;          // col pair
    const float* wmat = br ? wg : wlin;
    const float (*amat)[NHID] = br ? ss : ahs;
    f32x2 acc[8] = {{0,0},{0,0},{0,0},{0,0},{0,0},{0,0},{0,0},{0,0}};
    int kbase = kq * 32;
    for (int k4 = 0; k4 < 8; ++k4) {
        int k = kbase + 4 * k4;
        f32x4 a0 = *(const f32x4*)&amat[0][k];
        f32x4 a1 = *(const f32x4*)&amat[1][k];
        f32x4 a2 = *(const f32x4*)&amat[2][k];
        f32x4 a3 = *(const f32x4*)&amat[3][k];
        f32x4 a4 = *(const f32x4*)&amat[4][k];
        f32x4 a5 = *(const f32x4*)&amat[5][k];
        f32x4 a6 = *(const f32x4*)&amat[6][k];
        f32x4 a7 = *(const f32x4*)&amat[7][k];
        f32x2 w0 = ((const f32x2*)&wmat[(size_t)(k + 0) * NHID])[cp];
        f32x2 w1 = ((const f32x2*)&wmat[(size_t)(k + 1) * NHID])[cp];
        f32x2 w2 = ((const f32x2*)&wmat[(size_t)(k + 2) * NHID])[cp];
        f32x2 w3 = ((const f32x2*)&wmat[(size_t)(k + 3) * NHID])[cp];
        acc[0] += a0.x * w0 + a0.y * w1 + a0.z * w2 + a0.w * w3;
        acc[1] += a1.x * w0 + a1.y * w1 + a1.z * w2 + a1.w * w3;
        acc[2] += a2.x * w0 + a2.y * w1 + a2.z * w2 + a2.w * w3;
        acc[3] += a3.x * w0 + a3.y * w1 + a3.z * w2 + a3.w * w3;
        acc[4] += a4.x * w0 + a4.y * w1 + a4.z * w2 + a4.w * w3;
        acc[5] += a5.x * w0 + a5.y * w1 + a5.z * w2 + a5.w * w3;
        acc[6] += a6.x * w0 + a6.y * w1 + a6.z * w2 + a6.w * w3;
        acc[7] += a7.x * w0 + a7.y * w1 + a7.z * w2 + a7.w * w3;
    }

    // kq=1..3 partials -> LDS
    if (kq != 0) {
#pragma unroll
        for (int rr = 0; rr < 8; ++rr)
            ((f32x2*)&red[kq - 1][br][rr][0])[cp] = acc[rr];
    }
    __syncthreads();
    // kq=0 combines
    if (kq == 0) {
#pragma unroll
        for (int rr = 0; rr < 8; ++rr) {
            f32x2 p0 = ((const f32x2*)&red[0][br][rr][0])[cp];
            f32x2 p1 = ((const f32x2*)&red[1][br][rr][0])[cp];
            f32x2 p2 = ((const f32x2*)&red[2][br][rr][0])[cp];
            acc[rr] += p0 + p1 + p2;
        }
    }
    // gcnii epilogue on br1/kq0
    f32x2 gv[8];
    if (br == 1 && kq == 0) {
        f32x2 bgv = ((const f32x2*)bg)[cp];
        float omb = 1.0f - beta;
#pragma unroll
        for (int rr = 0; rr < 8; ++rr) {
            f32x2 sv = ((const f32x2*)&ss[rr][0])[cp];
            f32x2 t = omb * sv + beta * acc[rr] + bgv;
            gv[rr].x = fmaxf(t.x, 0.f);
            gv[rr].y = fmaxf(t.y, 0.f);
        }
    }
    __syncthreads();            // red reads complete
    if (br == 1 && kq == 0) {
#pragma unroll
        for (int rr = 0; rr < 8; ++rr)
            ((f32x2*)&red[0][0][rr][0])[cp] = gv[rr];
    }
    __syncthreads();            // g visible

    if (!final_layer) {
        if (br == 0 && kq == 0) {
            f32x2 blv = ((const f32x2*)blin)[cp];
#pragma unroll
            for (int rr = 0; rr < 8; ++rr) {
                int row = r0 + rr;
                f32x2 g = ((const f32x2*)&red[0][0][rr][0])[cp];
                f32x2 o = acc[rr] + blv + g;
                ((f32x2*)htout)[(size_t)row * 64 + cp] = dinv[row] * o;
            }
        }
    } else {
        // stage h = lin + g into ss, then fcout: out = h @ fow + fob
        if (br == 0 && kq == 0) {
            f32x2 blv = ((const f32x2*)blin)[cp];
#pragma unroll
            for (int rr = 0; rr < 8; ++rr) {
                f32x2 g = ((const f32x2*)&red[0][0][rr][0])[cp];
                ((f32x2*)&ss[rr][0])[cp] = acc[rr] + blv + g;
            }
        }
        __syncthreads();
        int rr2 = tid >> 6, c2 = tid & 63;   // 8 waves -> 8 rows, 1 each
        if (c2 < NCLS) {
            float a = fob[c2];
            for (int k = 0; k < NHID; ++k)
                a += ss[rr2][k] * fow[k * NCLS + c2];
            out[(size_t)(r0 + rr2) * NCLS + c2] = a;
        }
    }
}

extern "C" void kernel_launch(void* const* d_in, const int* in_sizes, int n_in,
                              void* d_out, int out_size, void* d_ws, size_t ws_size,
                              hipStream_t stream) {
    const float* x        = (const float*)d_in[0];
    const float* adj      = (const float*)d_in[1];
    const float* fc_in_w  = (const float*)d_in[2];
    const float* fc_in_b  = (const float*)d_in[3];
    const float* c        = (const float*)d_in[4];
    const float* w_gcnii  = (const float*)d_in[5];
    const float* b_gcnii  = (const float*)d_in[6];
    const float* w_lin    = (const float*)d_in[7];
    const float* b_lin    = (const float*)d_in[8];
    const float* fc_out_w = (const float*)d_in[9];
    const float* fc_out_b = (const float*)d_in[10];
    float* out = (float*)d_out;

    char* ws = (char*)d_ws;
    size_t off = 0;
    auto alloc = [&](size_t bytes) -> void* {
        void* p = ws + off;
        off += (bytes + 255) & ~(size_t)255;
        return p;
    };
    float* dinv = (float*)alloc((size_t)NROWS * 4);
    int*   cnts = (int*)  alloc((size_t)NROWS * 4);
    int*   cols = (int*)  alloc((size_t)NROWS * CAP * 4);
    float* hA   = (float*)alloc((size_t)NROWS * NHID * 4);
    float* h0   = (float*)alloc((size_t)NROWS * NHID * 4);
    float* htA  = (float*)alloc((size_t)NROWS * NHID * 4);
    float* htB  = (float*)alloc((size_t)NROWS * NHID * 4);

    k_pre<<<FCIN_BLOCKS + CSR_BLOCKS, 256, 0, stream>>>(
        x, fc_in_w, fc_in_b, c, adj, hA, h0, dinv, cnts, cols);

    // layer 0: edge-dinv gather from hA (no k_scale); layers 1-3: ht-based
    const float* hin[4] = {hA, htA, htB, htA};
    float* hout[4]      = {htA, htB, htA, nullptr};
    for (int i = 0; i < 4; ++i) {
        float beta = logf(0.5f / (float)(i + 1) + 1.0f);
        k_layer<<<NROWS / ROWS_PB, 512, 0, stream>>>(
            hin[i], h0, dinv, cnts, cols,
            w_lin + (size_t)i * NHID * NHID, b_lin + (size_t)i * NHID,
            w_gcnii + (size_t)i * NHID * NHID, b_gcnii + (size_t)i * NHID,
            beta, hout[i], fc_out_w, fc_out_b, out,
            (i == 0) ? 1 : 0, (i == 3) ? 1 : 0);
    }
}

// Round 15
// 186.043 us; speedup vs baseline: 1.0683x; 1.0683x over previous
//
#include <hip/hip_runtime.h>
#include <math.h>

#define NROWS 8192
#define NFEATD 500
#define NHID 128
#define NCLS 40
#define CAP 64            // max nnz/row (mean ~16.4, binomial max ~41)
#define FCIN_BLOCKS (NROWS / 8)   // 1024
#define CSR_BLOCKS  (NROWS / 4)   // 2048
#define ROWS_PB 8                 // rows per k_layer block (grid = 1024)

typedef float f32x4 __attribute__((ext_vector_type(4)));
typedef float f32x2 __attribute__((ext_vector_type(2)));

// ---------------------------------------------------------------------------
// Kernel 1 (heterogeneous): blocks [0,1024) do fcin, blocks [1024,3072) do
// CSR build. (R4/R9/R12/R13-verbatim.)
// ---------------------------------------------------------------------------
__global__ __launch_bounds__(256) void k_pre(
    const float* __restrict__ x, const float* __restrict__ w,
    const float* __restrict__ b, const float* __restrict__ c,
    const float* __restrict__ adj,
    float* __restrict__ h, float* __restrict__ h0,
    float* __restrict__ dinv, int* __restrict__ cnts, int* __restrict__ cols)
{
    __shared__ float xs[8][504];
    int tid = threadIdx.x;
    if (blockIdx.x < FCIN_BLOCKS) {
        int col = tid & 127;
        int rg = tid >> 7;
        int r0 = blockIdx.x * 8;
        for (int rr = 0; rr < 8; ++rr)
            for (int k = tid; k < NFEATD; k += 256)
                xs[rr][k] = x[(size_t)(r0 + rr) * NFEATD + k];
        __syncthreads();
        float bias = b[col];
        float acc[4] = {bias, bias, bias, bias};
        for (int k4 = 0; k4 < NFEATD / 4; ++k4) {
            int k = k4 * 4;
            f32x4 a0 = *(const f32x4*)&xs[rg * 4 + 0][k];
            f32x4 a1 = *(const f32x4*)&xs[rg * 4 + 1][k];
            f32x4 a2 = *(const f32x4*)&xs[rg * 4 + 2][k];
            f32x4 a3 = *(const f32x4*)&xs[rg * 4 + 3][k];
            float w0 = w[(k + 0) * NHID + col];
            float w1 = w[(k + 1) * NHID + col];
            float w2 = w[(k + 2) * NHID + col];
            float w3 = w[(k + 3) * NHID + col];
            acc[0] += a0.x * w0 + a0.y * w1 + a0.z * w2 + a0.w * w3;
            acc[1] += a1.x * w0 + a1.y * w1 + a1.z * w2 + a1.w * w3;
            acc[2] += a2.x * w0 + a2.y * w1 + a2.z * w2 + a2.w * w3;
            acc[3] += a3.x * w0 + a3.y * w1 + a3.z * w2 + a3.w * w3;
        }
        float cv = c[col];
#pragma unroll
        for (int rr = 0; rr < 4; ++rr) {
            float hv = 0.9f * fmaxf(acc[rr], 0.0f) + 0.1f * cv;
            size_t o = (size_t)(r0 + rg * 4 + rr) * NHID + col;
            h[o] = hv;
            h0[o] = hv;
        }
    } else {
        int bid = blockIdx.x - FCIN_BLOCKS;
        int r = bid * 4 + (tid >> 6);
        int lane = tid & 63;
        const f32x4* row4 = (const f32x4*)(adj + (size_t)r * NROWS);
        int* mycols = cols + (size_t)r * CAP;
        unsigned long long lt = (1ull << lane) - 1ull;
        int cnt = 0;
        for (int it = 0; it < NROWS / 256; ++it) {
            f32x4 v = __builtin_nontemporal_load(&row4[it * 64 + lane]);
            int base = it * 256 + 4 * lane;
            bool nz; unsigned long long m;
            nz = (v.x != 0.0f); m = __ballot(nz);
            if (nz) { int p = cnt + __popcll(m & lt); mycols[p < CAP ? p : CAP - 1] = base; }
            cnt += __popcll(m);
            nz = (v.y != 0.0f); m = __ballot(nz);
            if (nz) { int p = cnt + __popcll(m & lt); mycols[p < CAP ? p : CAP - 1] = base + 1; }
            cnt += __popcll(m);
            nz = (v.z != 0.0f); m = __ballot(nz);
            if (nz) { int p = cnt + __popcll(m & lt); mycols[p < CAP ? p : CAP - 1] = base + 2; }
            cnt += __popcll(m);
            nz = (v.w != 0.0f); m = __ballot(nz);
            if (nz) { int p = cnt + __popcll(m & lt); mycols[p < CAP ? p : CAP - 1] = base + 3; }
            cnt += __popcll(m);
        }
        if (lane == 0) {
            cnts[r] = cnt < CAP ? cnt : CAP;
            dinv[r] = rsqrtf((float)cnt + 1.0f);
        }
    }
}

// ---------------------------------------------------------------------------
// Kernel 1b: ht = dinv (row-wise) * h.  (R9-verbatim)
// ---------------------------------------------------------------------------
__global__ __launch_bounds__(256) void k_scale(
    const float* __restrict__ h, const float* __restrict__ dinv,
    float* __restrict__ ht)
{
    int gid = blockIdx.x * 256 + threadIdx.x;   // float2 index
    float2 v = ((const float2*)h)[gid];
    float d = dinv[gid >> 6];
    ((float2*)ht)[gid] = make_float2(v.x * d, v.y * d);
}

// ---------------------------------------------------------------------------
// Kernel 2 (per layer): gather (R9-verbatim) then split-matrix + SPLIT-K GEMM:
//   br = tid>>7 selects matrix (0: ahs@wlin, 1: ss@wg)
//   kh = (tid>>6)&1 selects k-half (0..63 / 64..127)  -> 16 k4 iters per wave
//   cp = tid&63 -> cols {2cp, 2cp+1}, f32x2 weights (each weight read ONCE)
// (R13-verbatim: proven 186.4 us, best known.)
// ---------------------------------------------------------------------------
__global__ __launch_bounds__(256) void k_layer(
    const float* __restrict__ ht, const float* __restrict__ h0,
    const float* __restrict__ dinv, const int* __restrict__ cnts,
    const int* __restrict__ cols,
    const float* __restrict__ wlin, const float* __restrict__ blin,
    const float* __restrict__ wg, const float* __restrict__ bg,
    float beta, float* __restrict__ htout,
    const float* __restrict__ fow, const float* __restrict__ fob,
    float* __restrict__ out, int final_layer)
{
    __shared__ float ahs[ROWS_PB][NHID];
    __shared__ float ss[ROWS_PB][NHID];
    __shared__ float red[2][ROWS_PB][NHID];   // kh=1 partials; red[0] reused for g
    int tid = threadIdx.x;
    int lane = tid & 63;
    int wid = tid >> 6;
    int r0 = blockIdx.x * ROWS_PB;
    const float2* ht2 = (const float2*)ht;
    const float2* h02 = (const float2*)h0;

    // ---- gather phase: wave wid handles rows 2*wid, 2*wid+1 (R9-verbatim) --
    for (int rr = 2 * wid; rr < 2 * wid + 2; ++rr) {
        int r = r0 + rr;
        int n = cnts[r];
        const int* mc = cols + (size_t)r * CAP;
        float ax = 0.f, ay = 0.f;
        int e = 0;
        for (; e + 4 <= n; e += 4) {
            int j0 = mc[e], j1 = mc[e + 1], j2 = mc[e + 2], j3 = mc[e + 3];
            float2 v0 = ht2[(size_t)j0 * 64 + lane];
            float2 v1 = ht2[(size_t)j1 * 64 + lane];
            float2 v2 = ht2[(size_t)j2 * 64 + lane];
            float2 v3 = ht2[(size_t)j3 * 64 + lane];
            ax += v0.x + v1.x + v2.x + v3.x;
            ay += v0.y + v1.y + v2.y + v3.y;
        }
        for (; e < n; ++e) {
            int j = mc[e];
            float2 v = ht2[(size_t)j * 64 + lane];
            ax += v.x;
            ay += v.y;
        }
        float di = dinv[r];
        float2 ti = ht2[(size_t)r * 64 + lane];   // ti = dinv[r]*h[r]
        float gx = di * (ax + ti.x);
        float gy = di * (ay + ti.y);
        float2 h0v = h02[(size_t)r * 64 + lane];
        ((float2*)&ahs[rr][0])[lane] = make_float2(gx, gy);
        ((float2*)&ss[rr][0])[lane] =
            make_float2(0.9f * gx + 0.1f * h0v.x, 0.9f * gy + 0.1f * h0v.y);
    }
    __syncthreads();

    // ---- split-k split-matrix GEMM ----
    int br = tid >> 7;          // matrix select (wave-uniform)
    int kh = (tid >> 6) & 1;    // k-half (wave-uniform)
    int cp = tid & 63;          // col pair: cols 2cp, 2cp+1
    const float* wmat = br ? wg : wlin;
    const float (*amat)[NHID] = br ? ss : ahs;
    f32x2 acc[8] = {{0,0},{0,0},{0,0},{0,0},{0,0},{0,0},{0,0},{0,0}};
    int kbase = kh * 64;
    for (int k4 = 0; k4 < 16; ++k4) {
        int k = kbase + 4 * k4;
        f32x4 a0 = *(const f32x4*)&amat[0][k];
        f32x4 a1 = *(const f32x4*)&amat[1][k];
        f32x4 a2 = *(const f32x4*)&amat[2][k];
        f32x4 a3 = *(const f32x4*)&amat[3][k];
        f32x4 a4 = *(const f32x4*)&amat[4][k];
        f32x4 a5 = *(const f32x4*)&amat[5][k];
        f32x4 a6 = *(const f32x4*)&amat[6][k];
        f32x4 a7 = *(const f32x4*)&amat[7][k];
        f32x2 w0 = ((const f32x2*)&wmat[(size_t)(k + 0) * NHID])[cp];
        f32x2 w1 = ((const f32x2*)&wmat[(size_t)(k + 1) * NHID])[cp];
        f32x2 w2 = ((const f32x2*)&wmat[(size_t)(k + 2) * NHID])[cp];
        f32x2 w3 = ((const f32x2*)&wmat[(size_t)(k + 3) * NHID])[cp];
        acc[0] += a0.x * w0 + a0.y * w1 + a0.z * w2 + a0.w * w3;
        acc[1] += a1.x * w0 + a1.y * w1 + a1.z * w2 + a1.w * w3;
        acc[2] += a2.x * w0 + a2.y * w1 + a2.z * w2 + a2.w * w3;
        acc[3] += a3.x * w0 + a3.y * w1 + a3.z * w2 + a3.w * w3;
        acc[4] += a4.x * w0 + a4.y * w1 + a4.z * w2 + a4.w * w3;
        acc[5] += a5.x * w0 + a5.y * w1 + a5.z * w2 + a5.w * w3;
        acc[6] += a6.x * w0 + a6.y * w1 + a6.z * w2 + a6.w * w3;
        acc[7] += a7.x * w0 + a7.y * w1 + a7.z * w2 + a7.w * w3;
    }

    // kh=1 partials -> LDS
    if (kh == 1) {
#pragma unroll
        for (int rr = 0; rr < 8; ++rr)
            ((f32x2*)&red[br][rr][0])[cp] = acc[rr];
    }
    __syncthreads();
    // kh=0 combines
    if (kh == 0) {
#pragma unroll
        for (int rr = 0; rr < 8; ++rr)
            acc[rr] += ((const f32x2*)&red[br][rr][0])[cp];
    }
    // gcnii epilogue on br1/kh0 (reads ss before red[0] is overwritten)
    f32x2 gv[8];
    if (br == 1 && kh == 0) {
        f32x2 bgv = ((const f32x2*)bg)[cp];
        float omb = 1.0f - beta;
#pragma unroll
        for (int rr = 0; rr < 8; ++rr) {
            f32x2 sv = ((const f32x2*)&ss[rr][0])[cp];
            f32x2 t = omb * sv + beta * acc[rr] + bgv;
            gv[rr].x = fmaxf(t.x, 0.f);
            gv[rr].y = fmaxf(t.y, 0.f);
        }
    }
    __syncthreads();            // red reads complete
    if (br == 1 && kh == 0) {
#pragma unroll
        for (int rr = 0; rr < 8; ++rr)
            ((f32x2*)&red[0][rr][0])[cp] = gv[rr];
    }
    __syncthreads();            // g visible

    if (!final_layer) {
        if (br == 0 && kh == 0) {
            f32x2 blv = ((const f32x2*)blin)[cp];
#pragma unroll
            for (int rr = 0; rr < 8; ++rr) {
                int row = r0 + rr;
                f32x2 g = ((const f32x2*)&red[0][rr][0])[cp];
                f32x2 o = acc[rr] + blv + g;
                ((f32x2*)htout)[(size_t)row * 64 + cp] = dinv[row] * o;
            }
        }
    } else {
        // stage h = lin + g into ss, then fcout: out = h @ fow + fob
        if (br == 0 && kh == 0) {
            f32x2 blv = ((const f32x2*)blin)[cp];
#pragma unroll
            for (int rr = 0; rr < 8; ++rr) {
                f32x2 g = ((const f32x2*)&red[0][rr][0])[cp];
                ((f32x2*)&ss[rr][0])[cp] = acc[rr] + blv + g;
            }
        }
        __syncthreads();
        int rr2 = tid >> 6, c2 = tid & 63;
        if (c2 < NCLS) {
#pragma unroll
            for (int half = 0; half < 2; ++half) {
                int lr = half * 4 + rr2;
                float a = fob[c2];
                for (int k = 0; k < NHID; ++k)
                    a += ss[lr][k] * fow[k * NCLS + c2];
                out[(size_t)(r0 + lr) * NCLS + c2] = a;
            }
        }
    }
}

extern "C" void kernel_launch(void* const* d_in, const int* in_sizes, int n_in,
                              void* d_out, int out_size, void* d_ws, size_t ws_size,
                              hipStream_t stream) {
    const float* x        = (const float*)d_in[0];
    const float* adj      = (const float*)d_in[1];
    const float* fc_in_w  = (const float*)d_in[2];
    const float* fc_in_b  = (const float*)d_in[3];
    const float* c        = (const float*)d_in[4];
    const float* w_gcnii  = (const float*)d_in[5];
    const float* b_gcnii  = (const float*)d_in[6];
    const float* w_lin    = (const float*)d_in[7];
    const float* b_lin    = (const float*)d_in[8];
    const float* fc_out_w = (const float*)d_in[9];
    const float* fc_out_b = (const float*)d_in[10];
    float* out = (float*)d_out;

    char* ws = (char*)d_ws;
    size_t off = 0;
    auto alloc = [&](size_t bytes) -> void* {
        void* p = ws + off;
        off += (bytes + 255) & ~(size_t)255;
        return p;
    };
    float* dinv = (float*)alloc((size_t)NROWS * 4);
    int*   cnts = (int*)  alloc((size_t)NROWS * 4);
    int*   cols = (int*)  alloc((size_t)NROWS * CAP * 4);
    float* hA   = (float*)alloc((size_t)NROWS * NHID * 4);
    float* h0   = (float*)alloc((size_t)NROWS * NHID * 4);
    float* htA  = (float*)alloc((size_t)NROWS * NHID * 4);
    float* htB  = (float*)alloc((size_t)NROWS * NHID * 4);

    k_pre<<<FCIN_BLOCKS + CSR_BLOCKS, 256, 0, stream>>>(
        x, fc_in_w, fc_in_b, c, adj, hA, h0, dinv, cnts, cols);
    k_scale<<<NROWS * 64 / 256, 256, 0, stream>>>(hA, dinv, htA);

    float* htb[2] = {htA, htB};
    for (int i = 0; i < 4; ++i) {
        float beta = logf(0.5f / (float)(i + 1) + 1.0f);
        k_layer<<<NROWS / ROWS_PB, 256, 0, stream>>>(
            htb[i & 1], h0, dinv, cnts, cols,
            w_lin + (size_t)i * NHID * NHID, b_lin + (size_t)i * NHID,
            w_gcnii + (size_t)i * NHID * NHID, b_gcnii + (size_t)i * NHID,
            beta, htb[(i + 1) & 1],
            fc_out_w, fc_out_b, out, (i == 3) ? 1 : 0);
    }
}